// Round 13
// baseline (229.754 us; speedup 1.0000x reference)
//
#include <hip/hip_runtime.h>
#include <hip/hip_bf16.h>

typedef _Float16 f16;
typedef _Float16 f16x4 __attribute__((ext_vector_type(4)));
typedef _Float16 f16x8 __attribute__((ext_vector_type(8)));
typedef float f32x4 __attribute__((ext_vector_type(4)));

#define NB 16
#define NN 1024
#define HH 256
#define NE 16384
#define NL 4
#define NM (NB * NN)   // 16384 rows

// ---------------- small utility kernels ----------------

__global__ void cvt_f32_f16(const float* __restrict__ s, f16* __restrict__ d, int n) {
    int i = blockIdx.x * 256 + threadIdx.x;
    if (i < n) d[i] = (f16)s[i];
}

__global__ void cvt_f32_f16v(const float* __restrict__ s, f16* __restrict__ d, int n8) {
    int i = blockIdx.x * 256 + threadIdx.x;
    if (i < n8) {
        const float4* p = (const float4*)(s + (size_t)i * 8);
        float4 a = p[0], b = p[1];
        f16x8 v;
        v[0] = (f16)a.x; v[1] = (f16)a.y; v[2] = (f16)a.z; v[3] = (f16)a.w;
        v[4] = (f16)b.x; v[5] = (f16)b.y; v[6] = (f16)b.z; v[7] = (f16)b.w;
        *(f16x8*)(d + (size_t)i * 8) = v;
    }
}

__global__ void zero_i32(int* p, int n) {
    int i = blockIdx.x * 256 + threadIdx.x;
    if (i < n) p[i] = 0;
}

__global__ void hist_kernel(const int* __restrict__ dst, int* cnt) {
    int e = blockIdx.x * 256 + threadIdx.x;
    if (e < NE) atomicAdd(&cnt[dst[e]], 1);
}

__global__ __launch_bounds__(1024) void scan_kernel(const int* __restrict__ cnt,
                                                    int* __restrict__ offs,
                                                    int* __restrict__ cur) {
    __shared__ int s[1024];
    int i = threadIdx.x;
    int c = cnt[i];
    s[i] = c;
    __syncthreads();
    for (int ofs = 1; ofs < 1024; ofs <<= 1) {
        int v = (i >= ofs) ? s[i - ofs] : 0;
        __syncthreads();
        s[i] += v;
        __syncthreads();
    }
    offs[i + 1] = s[i];
    if (i == 0) offs[0] = 0;
    cur[i] = s[i] - c;
}

__global__ void fill_kernel(const int* __restrict__ src, const int* __restrict__ dst,
                            int* cur, int* __restrict__ ssrc) {
    int e = blockIdx.x * 256 + threadIdx.x;
    if (e < NE) {
        int pos = atomicAdd(&cur[dst[e]], 1);
        ssrc[pos] = src[e];
    }
}

// ---------------- Wc = w_ih @ W[l]^T  (per layer), fp16 MFMA ----------------
__global__ __launch_bounds__(256) void wct_gemm(const f16* __restrict__ wih,
                                                const f16* __restrict__ wl,
                                                f16* __restrict__ wct) {
    int wid = threadIdx.x >> 6, lane = threadIdx.x & 63;
    int tile = blockIdx.x * 4 + wid;
    int l = tile / 768, rem = tile % 768;
    int jt = rem / 16, ht = rem % 16;
    const f16* A = wih + (size_t)(jt * 16 + (lane & 15)) * 256 + (lane >> 4) * 8;
    const f16* B = wl + (size_t)l * 65536 + (size_t)(ht * 16 + (lane & 15)) * 256 + (lane >> 4) * 8;
    f32x4 acc;
    for (int r = 0; r < 4; ++r) acc[r] = 0.f;
    for (int k = 0; k < 256; k += 32) {
        f16x8 a = *(const f16x8*)(A + k);
        f16x8 b = *(const f16x8*)(B + k);
        acc = __builtin_amdgcn_mfma_f32_16x16x32_f16(a, b, acc, 0, 0, 0);
    }
    int col = lane & 15, row0 = (lane >> 4) * 4;
    for (int r = 0; r < 4; ++r)
        wct[(size_t)l * 196608 + (size_t)(jt * 16 + row0 + r) * 256 + ht * 16 + col] = (f16)acc[r];
}

// ---------------- aggregation (fast path): XCD-affine per batch ----------------
__global__ __launch_bounds__(256) void agg_f16(const f16* __restrict__ xh,
                                               const int* __restrict__ offs,
                                               const int* __restrict__ ssrc,
                                               f16* __restrict__ ab) {
    int bid = blockIdx.x;
    int b = (bid & 7) + ((bid >> 11) << 3);
    int n = ((bid >> 3) & 255) * 4 + (threadIdx.x >> 6);
    int lane = threadIdx.x & 63;
    const f16* xb = xh + ((size_t)b << 18);
    int e0 = offs[n], e1 = offs[n + 1];
    float s0 = 0.f, s1 = 0.f, s2 = 0.f, s3 = 0.f;
    int p = e0;
    for (; p + 1 < e1; p += 2) {
        int i0 = ssrc[p], i1 = ssrc[p + 1];
        f16x4 v0 = *(const f16x4*)(xb + (((size_t)i0) << 8) + lane * 4);
        f16x4 v1 = *(const f16x4*)(xb + (((size_t)i1) << 8) + lane * 4);
        s0 += (float)v0[0] + (float)v1[0];
        s1 += (float)v0[1] + (float)v1[1];
        s2 += (float)v0[2] + (float)v1[2];
        s3 += (float)v0[3] + (float)v1[3];
    }
    if (p < e1) {
        f16x4 v0 = *(const f16x4*)(xb + (((size_t)ssrc[p]) << 8) + lane * 4);
        s0 += (float)v0[0]; s1 += (float)v0[1]; s2 += (float)v0[2]; s3 += (float)v0[3];
    }
    int row = (b << 10) + n;
    f16x4 o; o[0] = (f16)s0; o[1] = (f16)s1; o[2] = (f16)s2; o[3] = (f16)s3;
    *(f16x4*)(ab + (size_t)row * 256 + lane * 4) = o;
}

// ---------------- aggregation (fallback fp32 path) ----------------
__global__ __launch_bounds__(256) void agg_f32(const float* __restrict__ x,
                                               const int* __restrict__ offs,
                                               const int* __restrict__ ssrc,
                                               f16* __restrict__ ab) {
    int row = blockIdx.x * 4 + (threadIdx.x >> 6);
    int lane = threadIdx.x & 63;
    int b = row >> 10, n = row & 1023;
    int e0 = offs[n], e1 = offs[n + 1];
    float s0 = 0.f, s1 = 0.f, s2 = 0.f, s3 = 0.f;
    const float* xb = x + ((size_t)b << 18);
    for (int p = e0; p < e1; ++p) {
        float4 v = *(const float4*)(xb + (((size_t)ssrc[p]) << 8) + lane * 4);
        s0 += v.x; s1 += v.y; s2 += v.z; s3 += v.w;
    }
    f16x4 o; o[0] = (f16)s0; o[1] = (f16)s1; o[2] = (f16)s2; o[3] = (f16)s3;
    *(f16x4*)(ab + (size_t)row * 512 + lane * 4) = o;
    float4 v = *(const float4*)(x + (size_t)row * 256 + lane * 4);
    f16x4 o2; o2[0] = (f16)v.x; o2[1] = (f16)v.y; o2[2] = (f16)v.z; o2[3] = (f16)v.w;
    *(f16x4*)(ab + (size_t)row * 512 + 256 + lane * 4) = o2;
}

// ---------------- fused GEMM + GRU v11: v10 + depth-2 register prefetch ----------------
// 256 thr / 4 waves (wm x wj = 2x2). Tile 64 rows x 32 cols x 6 groups.
// TWO ping-pong staging register sets: set s=t&1 holds tile t, written to LDS at
// step t, then immediately re-loaded with tile t+2. Loads get ~2 full steps to
// land; compiler's vmcnt before ds_write drains only the older set (in-order
// retire). Everything else identical to v10 (swizzle, grid, 20 KB LDS).
__global__ __launch_bounds__(256) void gemm_gru_v11(const f16* __restrict__ ab,
                                                    const f16* __restrict__ xh,
                                                    const f16* __restrict__ wct,
                                                    const f16* __restrict__ whh,
                                                    const float* __restrict__ bih,
                                                    const float* __restrict__ bhh,
                                                    float* __restrict__ out,
                                                    f16* __restrict__ xh_dst,
                                                    int wout, int wxh) {
    __shared__ __align__(16) f16 Ay[64 * 32];    // 4 KB
    __shared__ __align__(16) f16 Ax[64 * 32];    // 4 KB
    __shared__ __align__(16) f16 Bs[192 * 32];   // 12 KB

    const int tid = threadIdx.x;
    const int w = tid >> 6, lane = tid & 63;
    const int wm = w >> 1, wj = w & 1;
    const int fr = lane & 15, sg = lane >> 4;
    const int m0 = blockIdx.x * 64;
    const int j0 = blockIdx.y * 32;

    // ---- staging sources (k-invariant) + swizzled LDS write offsets ----
    const int rA = tid >> 2, cA = tid & 3;
    const f16* gy = ab + (size_t)(m0 + rA) * 256 + cA * 8;
    const f16* gx = xh + (size_t)(m0 + rA) * 256 + cA * 8;
    const int wA = rA * 32 + ((cA ^ ((rA >> 1) & 3)) * 8);
    const f16 *gb0, *gb1, *gb2;
    int wB0, wB1, wB2;
    {
        int u0 = tid, u1 = tid + 256, u2 = tid + 512;
        int rr0 = u0 >> 2, rr1 = u1 >> 2, rr2 = u2 >> 2;
        int g0 = rr0 >> 5, g1 = rr1 >> 5, g2 = rr2 >> 5;
        gb0 = ((g0 < 3) ? (wct + (size_t)(g0 * 256 + j0 + (rr0 & 31)) * 256)
                        : (whh + (size_t)((g0 - 3) * 256 + j0 + (rr0 & 31)) * 256)) + (u0 & 3) * 8;
        gb1 = ((g1 < 3) ? (wct + (size_t)(g1 * 256 + j0 + (rr1 & 31)) * 256)
                        : (whh + (size_t)((g1 - 3) * 256 + j0 + (rr1 & 31)) * 256)) + (u1 & 3) * 8;
        gb2 = ((g2 < 3) ? (wct + (size_t)(g2 * 256 + j0 + (rr2 & 31)) * 256)
                        : (whh + (size_t)((g2 - 3) * 256 + j0 + (rr2 & 31)) * 256)) + (u2 & 3) * 8;
        wB0 = rr0 * 32 + (((u0 & 3) ^ ((rr0 >> 1) & 3)) * 8);
        wB1 = rr1 * 32 + (((u1 & 3) ^ ((rr1 >> 1) & 3)) * 8);
        wB2 = rr2 * 32 + (((u2 & 3) ^ ((rr2 >> 1) & 3)) * 8);
    }

    // ---- swizzled read offsets (f16 units) ----
    int aoff[2];
#pragma unroll
    for (int mf = 0; mf < 2; ++mf) {
        int row = wm * 32 + mf * 16 + fr;
        aoff[mf] = row * 32 + ((sg ^ ((row >> 1) & 3)) * 8);
    }
    int boff[6];
#pragma unroll
    for (int g = 0; g < 6; ++g) {
        int row = g * 32 + wj * 16 + fr;
        boff[g] = row * 32 + ((sg ^ ((row >> 1) & 3)) * 8);
    }

    f32x4 acc[6][2];
#pragma unroll
    for (int g = 0; g < 6; ++g)
#pragma unroll
        for (int mf = 0; mf < 2; ++mf)
#pragma unroll
            for (int r = 0; r < 4; ++r) acc[g][mf][r] = 0.f;

    // two statically-named staging sets (ping-pong, all indices compile-time)
    f16x8 ry0, rx0, rb00, rb10, rb20;   // set 0
    f16x8 ry1, rx1, rb01, rb11, rb21;   // set 1

#define LOADSET0(KK)                           \
    do {                                       \
        ry0 = *(const f16x8*)(gy + (KK));      \
        rx0 = *(const f16x8*)(gx + (KK));      \
        rb00 = *(const f16x8*)(gb0 + (KK));    \
        rb10 = *(const f16x8*)(gb1 + (KK));    \
        rb20 = *(const f16x8*)(gb2 + (KK));    \
    } while (0)
#define LOADSET1(KK)                           \
    do {                                       \
        ry1 = *(const f16x8*)(gy + (KK));      \
        rx1 = *(const f16x8*)(gx + (KK));      \
        rb01 = *(const f16x8*)(gb0 + (KK));    \
        rb11 = *(const f16x8*)(gb1 + (KK));    \
        rb21 = *(const f16x8*)(gb2 + (KK));    \
    } while (0)
#define WRITESET0()                    \
    do {                               \
        *(f16x8*)(Ay + wA) = ry0;      \
        *(f16x8*)(Ax + wA) = rx0;      \
        *(f16x8*)(Bs + wB0) = rb00;    \
        *(f16x8*)(Bs + wB1) = rb10;    \
        *(f16x8*)(Bs + wB2) = rb20;    \
    } while (0)
#define WRITESET1()                    \
    do {                               \
        *(f16x8*)(Ay + wA) = ry1;      \
        *(f16x8*)(Ax + wA) = rx1;      \
        *(f16x8*)(Bs + wB0) = rb01;    \
        *(f16x8*)(Bs + wB1) = rb11;    \
        *(f16x8*)(Bs + wB2) = rb21;    \
    } while (0)

    LOADSET0(0);     // tile 0
    LOADSET1(32);    // tile 1

#pragma unroll
    for (int t = 0; t < 8; ++t) {
        if (t) __syncthreads();            // previous step's readers done
        if ((t & 1) == 0) WRITESET0();     // tile t (loaded at step t-2)
        else              WRITESET1();
        __syncthreads();
        if (t < 6) {                       // reuse the just-written set for tile t+2
            if ((t & 1) == 0) LOADSET0((t + 2) * 32);
            else              LOADSET1((t + 2) * 32);
        }

        f16x8 aY[2], aX[2];
        aY[0] = *(const f16x8*)(Ay + aoff[0]);
        aY[1] = *(const f16x8*)(Ay + aoff[1]);
        aX[0] = *(const f16x8*)(Ax + aoff[0]);
        aX[1] = *(const f16x8*)(Ax + aoff[1]);
#pragma unroll
        for (int g = 0; g < 6; ++g) {
            f16x8 bF = *(const f16x8*)(Bs + boff[g]);
#pragma unroll
            for (int mf = 0; mf < 2; ++mf) {
                acc[g][mf] = __builtin_amdgcn_mfma_f32_16x16x32_f16(
                    (g < 3) ? aY[mf] : aX[mf], bF, acc[g][mf], 0, 0, 0);
            }
        }
    }
#undef LOADSET0
#undef LOADSET1
#undef WRITESET0
#undef WRITESET1

    // ---- GRU epilogue ----
    const int j = j0 + wj * 16 + fr;
    const float bir = bih[j], biz = bih[j + 256], bin = bih[j + 512];
    const float bhr = bhh[j], bhz = bhh[j + 256], bhn = bhh[j + 512];
#pragma unroll
    for (int mf = 0; mf < 2; ++mf) {
#pragma unroll
        for (int r = 0; r < 4; ++r) {
            int row = m0 + wm * 32 + mf * 16 + sg * 4 + r;
            float gir = acc[0][mf][r] + bir;
            float giz = acc[1][mf][r] + biz;
            float gin = acc[2][mf][r] + bin;
            float ghr = acc[3][mf][r] + bhr;
            float ghz = acc[4][mf][r] + bhz;
            float ghn = acc[5][mf][r] + bhn;
            float rg = 1.f / (1.f + __expf(-(gir + ghr)));
            float zg = 1.f / (1.f + __expf(-(giz + ghz)));
            float ng = tanhf(gin + rg * ghn);
            float h = (float)xh[(size_t)row * 256 + j];
            float res = (1.f - zg) * ng + zg * h;
            if (wout) out[(size_t)row * 256 + j] = res;
            if (wxh) xh_dst[(size_t)row * 256 + j] = (f16)res;
        }
    }
}

// ---------------- old fused GEMM + GRU (fallback fp32 path) ----------------
__global__ __launch_bounds__(256) void gemm_gru_slow(const f16* __restrict__ ab,
                                                     const f16* __restrict__ wct,
                                                     const f16* __restrict__ whh,
                                                     const float* __restrict__ bih,
                                                     const float* __restrict__ bhh,
                                                     const float* __restrict__ x_src,
                                                     float* __restrict__ out) {
    __shared__ __align__(16) f16 As[2][64][40];
    __shared__ __align__(16) f16 Bs[6][32][40];

    int m0 = blockIdx.x * 64;
    int j0 = blockIdx.y * 32;
    int tid = threadIdx.x;
    int wid = tid >> 6, lane = tid & 63;

    f32x4 acc[6][2];
#pragma unroll
    for (int g = 0; g < 6; ++g)
#pragma unroll
        for (int jt = 0; jt < 2; ++jt)
#pragma unroll
            for (int r = 0; r < 4; ++r) acc[g][jt][r] = 0.f;

    int ar = tid >> 2, ac = (tid & 3) * 8;

    for (int kk = 0; kk < 256; kk += 32) {
        f16x8 a0 = *(const f16x8*)(ab + (size_t)(m0 + ar) * 512 + kk + ac);
        f16x8 a1 = *(const f16x8*)(ab + (size_t)(m0 + ar) * 512 + 256 + kk + ac);
        *(f16x8*)(&As[0][ar][ac]) = a0;
        *(f16x8*)(&As[1][ar][ac]) = a1;
#pragma unroll
        for (int i = 0; i < 3; ++i) {
            int idx = tid + i * 256;
            int g = idx >> 7;
            int r = (idx >> 2) & 31;
            int c = (idx & 3) * 8;
            const f16* src = (g < 3)
                ? (wct + (size_t)(j0 + g * 256 + r) * 256 + kk + c)
                : (whh + (size_t)(j0 + (g - 3) * 256 + r) * 256 + kk + c);
            *(f16x8*)(&Bs[g][r][c]) = *(const f16x8*)src;
        }
        __syncthreads();

        int fr = lane & 15, fo = (lane >> 4) * 8;
        f16x8 aF[2];
        aF[0] = *(const f16x8*)(&As[0][wid * 16 + fr][fo]);
        aF[1] = *(const f16x8*)(&As[1][wid * 16 + fr][fo]);
#pragma unroll
        for (int g = 0; g < 6; ++g) {
#pragma unroll
            for (int jt = 0; jt < 2; ++jt) {
                f16x8 bF = *(const f16x8*)(&Bs[g][jt * 16 + fr][fo]);
                acc[g][jt] = __builtin_amdgcn_mfma_f32_16x16x32_f16(
                    (g < 3) ? aF[0] : aF[1], bF, acc[g][jt], 0, 0, 0);
            }
        }
        __syncthreads();
    }

    int fr = lane & 15, frow = (lane >> 4) * 4;
#pragma unroll
    for (int jt = 0; jt < 2; ++jt) {
        int j = j0 + jt * 16 + fr;
        float bir = bih[j], biz = bih[j + 256], bin = bih[j + 512];
        float bhr = bhh[j], bhz = bhh[j + 256], bhn = bhh[j + 512];
#pragma unroll
        for (int r = 0; r < 4; ++r) {
            int row = m0 + wid * 16 + frow + r;
            float gir = acc[0][jt][r] + bir;
            float giz = acc[1][jt][r] + biz;
            float gin = acc[2][jt][r] + bin;
            float ghr = acc[3][jt][r] + bhr;
            float ghz = acc[4][jt][r] + bhz;
            float ghn = acc[5][jt][r] + bhn;
            float rg = 1.f / (1.f + __expf(-(gir + ghr)));
            float zg = 1.f / (1.f + __expf(-(giz + ghz)));
            float ng = tanhf(gin + rg * ghn);
            float h = x_src[(size_t)row * 256 + j];
            out[(size_t)row * 256 + j] = (1.f - zg) * ng + zg * h;
        }
    }
}

// ---------------- launch ----------------

extern "C" void kernel_launch(void* const* d_in, const int* in_sizes, int n_in,
                              void* d_out, int out_size, void* d_ws, size_t ws_size,
                              hipStream_t stream) {
    const float* emb = (const float*)d_in[0];
    const int* eidx = (const int*)d_in[1];
    const float* W = (const float*)d_in[2];
    const float* wih = (const float*)d_in[3];
    const float* whh = (const float*)d_in[4];
    const float* bih = (const float*)d_in[5];
    const float* bhh = (const float*)d_in[6];
    float* out = (float*)d_out;

    const size_t NEL = (size_t)NM * 256;
    f16* ab = (f16*)d_ws;
    f16* xhA = ab + NEL;
    f16* xhB = xhA + NEL;
    f16* wct_f = xhB + NEL;
    const size_t need = ((size_t)3 * NEL + 786432 + 196608 + 196608 + 262144) * 2 + 80000;
    bool fast = ws_size >= need;

    f16 *wct, *whh_h, *wih_h, *w_h;
    if (fast) {
        wct = wct_f;
    } else {
        wct = (f16*)((char*)d_ws + (size_t)16 * 1024 * 1024);
    }
    whh_h = wct + (size_t)4 * 768 * 256;
    wih_h = whh_h + (size_t)768 * 256;
    w_h = wih_h + (size_t)768 * 256;
    int* cnt = (int*)(w_h + (size_t)4 * 256 * 256);
    int* offs = cnt + 1024;
    int* cur = offs + 1056;
    int* ssrc = cur + 1024;

    cvt_f32_f16<<<(768 * 256 + 255) / 256, 256, 0, stream>>>(wih, wih_h, 768 * 256);
    cvt_f32_f16<<<(768 * 256 + 255) / 256, 256, 0, stream>>>(whh, whh_h, 768 * 256);
    cvt_f32_f16<<<(4 * 256 * 256 + 255) / 256, 256, 0, stream>>>(W, w_h, 4 * 256 * 256);

    zero_i32<<<4, 256, 0, stream>>>(cnt, 1024);
    hist_kernel<<<64, 256, 0, stream>>>(eidx + NE, cnt);
    scan_kernel<<<1, 1024, 0, stream>>>(cnt, offs, cur);
    fill_kernel<<<64, 256, 0, stream>>>(eidx, eidx + NE, cur, ssrc);

    wct_gemm<<<768, 256, 0, stream>>>(wih_h, w_h, wct);

    if (fast) {
        cvt_f32_f16v<<<(int)(NEL / 8 + 255) / 256, 256, 0, stream>>>(emb, xhA, (int)(NEL / 8));
        for (int l = 0; l < NL; ++l) {
            f16* xs = (l & 1) ? xhB : xhA;
            f16* xd = (l & 1) ? xhA : xhB;
            agg_f16<<<NM / 4, 256, 0, stream>>>(xs, offs, ssrc, ab);
            gemm_gru_v11<<<dim3(NM / 64, 8), 256, 0, stream>>>(
                ab, xs, wct + (size_t)l * 768 * 256, whh_h, bih, bhh,
                out, xd, (l == NL - 1) ? 1 : 0, (l < NL - 1) ? 1 : 0);
        }
    } else {
        const float* xs = emb;
        for (int l = 0; l < NL; ++l) {
            agg_f32<<<NM / 4, 256, 0, stream>>>(xs, offs, ssrc, ab);
            gemm_gru_slow<<<dim3(NM / 64, 8), 256, 0, stream>>>(
                ab, wct + (size_t)l * 768 * 256, whh_h, bih, bhh, xs, out);
            xs = out;
        }
    }
}

// Round 15
// 227.040 us; speedup vs baseline: 1.0120x; 1.0120x over previous
//
#include <hip/hip_runtime.h>
#include <hip/hip_bf16.h>

typedef _Float16 f16;
typedef _Float16 f16x4 __attribute__((ext_vector_type(4)));
typedef _Float16 f16x8 __attribute__((ext_vector_type(8)));
typedef float f32x4 __attribute__((ext_vector_type(4)));

#define NB 16
#define NN 1024
#define HH 256
#define NE 16384
#define NL 4
#define NM (NB * NN)   // 16384 rows

// ---------------- small utility kernels ----------------

__global__ void cvt_f32_f16(const float* __restrict__ s, f16* __restrict__ d, int n) {
    int i = blockIdx.x * 256 + threadIdx.x;
    if (i < n) d[i] = (f16)s[i];
}

__global__ void cvt_f32_f16v(const float* __restrict__ s, f16* __restrict__ d, int n8) {
    int i = blockIdx.x * 256 + threadIdx.x;
    if (i < n8) {
        const float4* p = (const float4*)(s + (size_t)i * 8);
        float4 a = p[0], b = p[1];
        f16x8 v;
        v[0] = (f16)a.x; v[1] = (f16)a.y; v[2] = (f16)a.z; v[3] = (f16)a.w;
        v[4] = (f16)b.x; v[5] = (f16)b.y; v[6] = (f16)b.z; v[7] = (f16)b.w;
        *(f16x8*)(d + (size_t)i * 8) = v;
    }
}

__global__ void zero_i32(int* p, int n) {
    int i = blockIdx.x * 256 + threadIdx.x;
    if (i < n) p[i] = 0;
}

__global__ void hist_kernel(const int* __restrict__ dst, int* cnt) {
    int e = blockIdx.x * 256 + threadIdx.x;
    if (e < NE) atomicAdd(&cnt[dst[e]], 1);
}

__global__ __launch_bounds__(1024) void scan_kernel(const int* __restrict__ cnt,
                                                    int* __restrict__ offs,
                                                    int* __restrict__ cur) {
    __shared__ int s[1024];
    int i = threadIdx.x;
    int c = cnt[i];
    s[i] = c;
    __syncthreads();
    for (int ofs = 1; ofs < 1024; ofs <<= 1) {
        int v = (i >= ofs) ? s[i - ofs] : 0;
        __syncthreads();
        s[i] += v;
        __syncthreads();
    }
    offs[i + 1] = s[i];
    if (i == 0) offs[0] = 0;
    cur[i] = s[i] - c;
}

__global__ void fill_kernel(const int* __restrict__ src, const int* __restrict__ dst,
                            int* cur, int* __restrict__ ssrc) {
    int e = blockIdx.x * 256 + threadIdx.x;
    if (e < NE) {
        int pos = atomicAdd(&cur[dst[e]], 1);
        ssrc[pos] = src[e];
    }
}

// ---------------- Wc = w_ih @ W[l]^T  (per layer), fp16 MFMA ----------------
__global__ __launch_bounds__(256) void wct_gemm(const f16* __restrict__ wih,
                                                const f16* __restrict__ wl,
                                                f16* __restrict__ wct) {
    int wid = threadIdx.x >> 6, lane = threadIdx.x & 63;
    int tile = blockIdx.x * 4 + wid;
    int l = tile / 768, rem = tile % 768;
    int jt = rem / 16, ht = rem % 16;
    const f16* A = wih + (size_t)(jt * 16 + (lane & 15)) * 256 + (lane >> 4) * 8;
    const f16* B = wl + (size_t)l * 65536 + (size_t)(ht * 16 + (lane & 15)) * 256 + (lane >> 4) * 8;
    f32x4 acc;
    for (int r = 0; r < 4; ++r) acc[r] = 0.f;
    for (int k = 0; k < 256; k += 32) {
        f16x8 a = *(const f16x8*)(A + k);
        f16x8 b = *(const f16x8*)(B + k);
        acc = __builtin_amdgcn_mfma_f32_16x16x32_f16(a, b, acc, 0, 0, 0);
    }
    int col = lane & 15, row0 = (lane >> 4) * 4;
    for (int r = 0; r < 4; ++r)
        wct[(size_t)l * 196608 + (size_t)(jt * 16 + row0 + r) * 256 + ht * 16 + col] = (f16)acc[r];
}

// ---------------- aggregation (fast path): XCD-affine per batch ----------------
__global__ __launch_bounds__(256) void agg_f16(const f16* __restrict__ xh,
                                               const int* __restrict__ offs,
                                               const int* __restrict__ ssrc,
                                               f16* __restrict__ ab) {
    int bid = blockIdx.x;
    int b = (bid & 7) + ((bid >> 11) << 3);
    int n = ((bid >> 3) & 255) * 4 + (threadIdx.x >> 6);
    int lane = threadIdx.x & 63;
    const f16* xb = xh + ((size_t)b << 18);
    int e0 = offs[n], e1 = offs[n + 1];
    float s0 = 0.f, s1 = 0.f, s2 = 0.f, s3 = 0.f;
    int p = e0;
    for (; p + 1 < e1; p += 2) {
        int i0 = ssrc[p], i1 = ssrc[p + 1];
        f16x4 v0 = *(const f16x4*)(xb + (((size_t)i0) << 8) + lane * 4);
        f16x4 v1 = *(const f16x4*)(xb + (((size_t)i1) << 8) + lane * 4);
        s0 += (float)v0[0] + (float)v1[0];
        s1 += (float)v0[1] + (float)v1[1];
        s2 += (float)v0[2] + (float)v1[2];
        s3 += (float)v0[3] + (float)v1[3];
    }
    if (p < e1) {
        f16x4 v0 = *(const f16x4*)(xb + (((size_t)ssrc[p]) << 8) + lane * 4);
        s0 += (float)v0[0]; s1 += (float)v0[1]; s2 += (float)v0[2]; s3 += (float)v0[3];
    }
    int row = (b << 10) + n;
    f16x4 o; o[0] = (f16)s0; o[1] = (f16)s1; o[2] = (f16)s2; o[3] = (f16)s3;
    *(f16x4*)(ab + (size_t)row * 256 + lane * 4) = o;
}

// ---------------- aggregation (fallback fp32 path) ----------------
__global__ __launch_bounds__(256) void agg_f32(const float* __restrict__ x,
                                               const int* __restrict__ offs,
                                               const int* __restrict__ ssrc,
                                               f16* __restrict__ ab) {
    int row = blockIdx.x * 4 + (threadIdx.x >> 6);
    int lane = threadIdx.x & 63;
    int b = row >> 10, n = row & 1023;
    int e0 = offs[n], e1 = offs[n + 1];
    float s0 = 0.f, s1 = 0.f, s2 = 0.f, s3 = 0.f;
    const float* xb = x + ((size_t)b << 18);
    for (int p = e0; p < e1; ++p) {
        float4 v = *(const float4*)(xb + (((size_t)ssrc[p]) << 8) + lane * 4);
        s0 += v.x; s1 += v.y; s2 += v.z; s3 += v.w;
    }
    f16x4 o; o[0] = (f16)s0; o[1] = (f16)s1; o[2] = (f16)s2; o[3] = (f16)s3;
    *(f16x4*)(ab + (size_t)row * 512 + lane * 4) = o;
    float4 v = *(const float4*)(x + (size_t)row * 256 + lane * 4);
    f16x4 o2; o2[0] = (f16)v.x; o2[1] = (f16)v.y; o2[2] = (f16)v.z; o2[3] = (f16)v.w;
    *(f16x4*)(ab + (size_t)row * 512 + 256 + lane * 4) = o2;
}

// ---------------- fused GEMM + GRU v10: proven best (R12, 226.9 us total) ----------------
// 256 thr / 4 waves arranged wm x wj = 2x2. Tile 64 rows x 32 cols x 6 groups.
// Wave (wm,wj): rows wm*32 + mf*16 (mf=2), cols wj*16. Per wave-step:
// 4 A-reads + 6 B-reads feed 12 MFMAs. Reg-staged LDS (ds_write anchors the
// global loads so the compiler cannot sink them), both-side XOR swizzle
// slot = chunk ^ ((row>>1)&3) (verified 0 bank conflicts), 2 barriers/step,
// t+1 loads issued right after the write-barrier -> full MFMA phase to land.
// 20 KB LDS, grid (256,8) = 2048 blocks = 8 blocks/CU.
__global__ __launch_bounds__(256) void gemm_gru_v10(const f16* __restrict__ ab,
                                                    const f16* __restrict__ xh,
                                                    const f16* __restrict__ wct,
                                                    const f16* __restrict__ whh,
                                                    const float* __restrict__ bih,
                                                    const float* __restrict__ bhh,
                                                    float* __restrict__ out,
                                                    f16* __restrict__ xh_dst,
                                                    int wout, int wxh) {
    __shared__ __align__(16) f16 Ay[64 * 32];    // 4 KB
    __shared__ __align__(16) f16 Ax[64 * 32];    // 4 KB
    __shared__ __align__(16) f16 Bs[192 * 32];   // 12 KB

    const int tid = threadIdx.x;
    const int w = tid >> 6, lane = tid & 63;
    const int wm = w >> 1, wj = w & 1;
    const int fr = lane & 15, sg = lane >> 4;
    const int m0 = blockIdx.x * 64;
    const int j0 = blockIdx.y * 32;

    // ---- staging sources (k-invariant) + swizzled LDS write offsets ----
    const int rA = tid >> 2, cA = tid & 3;
    const f16* gy = ab + (size_t)(m0 + rA) * 256 + cA * 8;
    const f16* gx = xh + (size_t)(m0 + rA) * 256 + cA * 8;
    const int wA = rA * 32 + ((cA ^ ((rA >> 1) & 3)) * 8);
    const f16 *gb0, *gb1, *gb2;
    int wB0, wB1, wB2;
    {
        int u0 = tid, u1 = tid + 256, u2 = tid + 512;
        int rr0 = u0 >> 2, rr1 = u1 >> 2, rr2 = u2 >> 2;
        int g0 = rr0 >> 5, g1 = rr1 >> 5, g2 = rr2 >> 5;
        gb0 = ((g0 < 3) ? (wct + (size_t)(g0 * 256 + j0 + (rr0 & 31)) * 256)
                        : (whh + (size_t)((g0 - 3) * 256 + j0 + (rr0 & 31)) * 256)) + (u0 & 3) * 8;
        gb1 = ((g1 < 3) ? (wct + (size_t)(g1 * 256 + j0 + (rr1 & 31)) * 256)
                        : (whh + (size_t)((g1 - 3) * 256 + j0 + (rr1 & 31)) * 256)) + (u1 & 3) * 8;
        gb2 = ((g2 < 3) ? (wct + (size_t)(g2 * 256 + j0 + (rr2 & 31)) * 256)
                        : (whh + (size_t)((g2 - 3) * 256 + j0 + (rr2 & 31)) * 256)) + (u2 & 3) * 8;
        wB0 = rr0 * 32 + (((u0 & 3) ^ ((rr0 >> 1) & 3)) * 8);
        wB1 = rr1 * 32 + (((u1 & 3) ^ ((rr1 >> 1) & 3)) * 8);
        wB2 = rr2 * 32 + (((u2 & 3) ^ ((rr2 >> 1) & 3)) * 8);
    }

    // ---- swizzled read offsets (f16 units) ----
    int aoff[2];
#pragma unroll
    for (int mf = 0; mf < 2; ++mf) {
        int row = wm * 32 + mf * 16 + fr;
        aoff[mf] = row * 32 + ((sg ^ ((row >> 1) & 3)) * 8);
    }
    int boff[6];
#pragma unroll
    for (int g = 0; g < 6; ++g) {
        int row = g * 32 + wj * 16 + fr;
        boff[g] = row * 32 + ((sg ^ ((row >> 1) & 3)) * 8);
    }

    f32x4 acc[6][2];
#pragma unroll
    for (int g = 0; g < 6; ++g)
#pragma unroll
        for (int mf = 0; mf < 2; ++mf)
#pragma unroll
            for (int r = 0; r < 4; ++r) acc[g][mf][r] = 0.f;

    f16x8 ry, rx, rb0, rb1, rb2;
#define LOADREGS(KK)                          \
    do {                                      \
        ry = *(const f16x8*)(gy + (KK));      \
        rx = *(const f16x8*)(gx + (KK));      \
        rb0 = *(const f16x8*)(gb0 + (KK));    \
        rb1 = *(const f16x8*)(gb1 + (KK));    \
        rb2 = *(const f16x8*)(gb2 + (KK));    \
    } while (0)

    LOADREGS(0);

#pragma unroll
    for (int t = 0; t < 8; ++t) {
        if (t) __syncthreads();            // previous step's readers done
        *(f16x8*)(Ay + wA) = ry;
        *(f16x8*)(Ax + wA) = rx;
        *(f16x8*)(Bs + wB0) = rb0;
        *(f16x8*)(Bs + wB1) = rb1;
        *(f16x8*)(Bs + wB2) = rb2;
        __syncthreads();
        if (t < 7) LOADREGS((t + 1) * 32); // in flight across the MFMA section

        f16x8 aY[2], aX[2];
        aY[0] = *(const f16x8*)(Ay + aoff[0]);
        aY[1] = *(const f16x8*)(Ay + aoff[1]);
        aX[0] = *(const f16x8*)(Ax + aoff[0]);
        aX[1] = *(const f16x8*)(Ax + aoff[1]);
#pragma unroll
        for (int g = 0; g < 6; ++g) {
            f16x8 bF = *(const f16x8*)(Bs + boff[g]);
#pragma unroll
            for (int mf = 0; mf < 2; ++mf) {
                acc[g][mf] = __builtin_amdgcn_mfma_f32_16x16x32_f16(
                    (g < 3) ? aY[mf] : aX[mf], bF, acc[g][mf], 0, 0, 0);
            }
        }
    }
#undef LOADREGS

    // ---- GRU epilogue ----
    const int j = j0 + wj * 16 + fr;
    const float bir = bih[j], biz = bih[j + 256], bin = bih[j + 512];
    const float bhr = bhh[j], bhz = bhh[j + 256], bhn = bhh[j + 512];
#pragma unroll
    for (int mf = 0; mf < 2; ++mf) {
#pragma unroll
        for (int r = 0; r < 4; ++r) {
            int row = m0 + wm * 32 + mf * 16 + sg * 4 + r;
            float gir = acc[0][mf][r] + bir;
            float giz = acc[1][mf][r] + biz;
            float gin = acc[2][mf][r] + bin;
            float ghr = acc[3][mf][r] + bhr;
            float ghz = acc[4][mf][r] + bhz;
            float ghn = acc[5][mf][r] + bhn;
            float rg = 1.f / (1.f + __expf(-(gir + ghr)));
            float zg = 1.f / (1.f + __expf(-(giz + ghz)));
            float ng = tanhf(gin + rg * ghn);
            float h = (float)xh[(size_t)row * 256 + j];
            float res = (1.f - zg) * ng + zg * h;
            if (wout) out[(size_t)row * 256 + j] = res;
            if (wxh) xh_dst[(size_t)row * 256 + j] = (f16)res;
        }
    }
}

// ---------------- old fused GEMM + GRU (fallback fp32 path) ----------------
__global__ __launch_bounds__(256) void gemm_gru_slow(const f16* __restrict__ ab,
                                                     const f16* __restrict__ wct,
                                                     const f16* __restrict__ whh,
                                                     const float* __restrict__ bih,
                                                     const float* __restrict__ bhh,
                                                     const float* __restrict__ x_src,
                                                     float* __restrict__ out) {
    __shared__ __align__(16) f16 As[2][64][40];
    __shared__ __align__(16) f16 Bs[6][32][40];

    int m0 = blockIdx.x * 64;
    int j0 = blockIdx.y * 32;
    int tid = threadIdx.x;
    int wid = tid >> 6, lane = tid & 63;

    f32x4 acc[6][2];
#pragma unroll
    for (int g = 0; g < 6; ++g)
#pragma unroll
        for (int jt = 0; jt < 2; ++jt)
#pragma unroll
            for (int r = 0; r < 4; ++r) acc[g][jt][r] = 0.f;

    int ar = tid >> 2, ac = (tid & 3) * 8;

    for (int kk = 0; kk < 256; kk += 32) {
        f16x8 a0 = *(const f16x8*)(ab + (size_t)(m0 + ar) * 512 + kk + ac);
        f16x8 a1 = *(const f16x8*)(ab + (size_t)(m0 + ar) * 512 + 256 + kk + ac);
        *(f16x8*)(&As[0][ar][ac]) = a0;
        *(f16x8*)(&As[1][ar][ac]) = a1;
#pragma unroll
        for (int i = 0; i < 3; ++i) {
            int idx = tid + i * 256;
            int g = idx >> 7;
            int r = (idx >> 2) & 31;
            int c = (idx & 3) * 8;
            const f16* src = (g < 3)
                ? (wct + (size_t)(j0 + g * 256 + r) * 256 + kk + c)
                : (whh + (size_t)(j0 + (g - 3) * 256 + r) * 256 + kk + c);
            *(f16x8*)(&Bs[g][r][c]) = *(const f16x8*)src;
        }
        __syncthreads();

        int fr = lane & 15, fo = (lane >> 4) * 8;
        f16x8 aF[2];
        aF[0] = *(const f16x8*)(&As[0][wid * 16 + fr][fo]);
        aF[1] = *(const f16x8*)(&As[1][wid * 16 + fr][fo]);
#pragma unroll
        for (int g = 0; g < 6; ++g) {
#pragma unroll
            for (int jt = 0; jt < 2; ++jt) {
                f16x8 bF = *(const f16x8*)(&Bs[g][jt * 16 + fr][fo]);
                acc[g][jt] = __builtin_amdgcn_mfma_f32_16x16x32_f16(
                    (g < 3) ? aF[0] : aF[1], bF, acc[g][jt], 0, 0, 0);
            }
        }
        __syncthreads();
    }

    int fr = lane & 15, frow = (lane >> 4) * 4;
#pragma unroll
    for (int jt = 0; jt < 2; ++jt) {
        int j = j0 + jt * 16 + fr;
        float bir = bih[j], biz = bih[j + 256], bin = bih[j + 512];
        float bhr = bhh[j], bhz = bhh[j + 256], bhn = bhh[j + 512];
#pragma unroll
        for (int r = 0; r < 4; ++r) {
            int row = m0 + wid * 16 + frow + r;
            float gir = acc[0][jt][r] + bir;
            float giz = acc[1][jt][r] + biz;
            float gin = acc[2][jt][r] + bin;
            float ghr = acc[3][jt][r] + bhr;
            float ghz = acc[4][jt][r] + bhz;
            float ghn = acc[5][jt][r] + bhn;
            float rg = 1.f / (1.f + __expf(-(gir + ghr)));
            float zg = 1.f / (1.f + __expf(-(giz + ghz)));
            float ng = tanhf(gin + rg * ghn);
            float h = x_src[(size_t)row * 256 + j];
            out[(size_t)row * 256 + j] = (1.f - zg) * ng + zg * h;
        }
    }
}

// ---------------- launch ----------------

extern "C" void kernel_launch(void* const* d_in, const int* in_sizes, int n_in,
                              void* d_out, int out_size, void* d_ws, size_t ws_size,
                              hipStream_t stream) {
    const float* emb = (const float*)d_in[0];
    const int* eidx = (const int*)d_in[1];
    const float* W = (const float*)d_in[2];
    const float* wih = (const float*)d_in[3];
    const float* whh = (const float*)d_in[4];
    const float* bih = (const float*)d_in[5];
    const float* bhh = (const float*)d_in[6];
    float* out = (float*)d_out;

    const size_t NEL = (size_t)NM * 256;
    f16* ab = (f16*)d_ws;
    f16* xhA = ab + NEL;
    f16* xhB = xhA + NEL;
    f16* wct_f = xhB + NEL;
    const size_t need = ((size_t)3 * NEL + 786432 + 196608 + 196608 + 262144) * 2 + 80000;
    bool fast = ws_size >= need;

    f16 *wct, *whh_h, *wih_h, *w_h;
    if (fast) {
        wct = wct_f;
    } else {
        wct = (f16*)((char*)d_ws + (size_t)16 * 1024 * 1024);
    }
    whh_h = wct + (size_t)4 * 768 * 256;
    wih_h = whh_h + (size_t)768 * 256;
    w_h = wih_h + (size_t)768 * 256;
    int* cnt = (int*)(w_h + (size_t)4 * 256 * 256);
    int* offs = cnt + 1024;
    int* cur = offs + 1056;
    int* ssrc = cur + 1024;

    cvt_f32_f16<<<(768 * 256 + 255) / 256, 256, 0, stream>>>(wih, wih_h, 768 * 256);
    cvt_f32_f16<<<(768 * 256 + 255) / 256, 256, 0, stream>>>(whh, whh_h, 768 * 256);
    cvt_f32_f16<<<(4 * 256 * 256 + 255) / 256, 256, 0, stream>>>(W, w_h, 4 * 256 * 256);

    zero_i32<<<4, 256, 0, stream>>>(cnt, 1024);
    hist_kernel<<<64, 256, 0, stream>>>(eidx + NE, cnt);
    scan_kernel<<<1, 1024, 0, stream>>>(cnt, offs, cur);
    fill_kernel<<<64, 256, 0, stream>>>(eidx, eidx + NE, cur, ssrc);

    wct_gemm<<<768, 256, 0, stream>>>(wih_h, w_h, wct);

    if (fast) {
        cvt_f32_f16v<<<(int)(NEL / 8 + 255) / 256, 256, 0, stream>>>(emb, xhA, (int)(NEL / 8));
        for (int l = 0; l < NL; ++l) {
            f16* xs = (l & 1) ? xhB : xhA;
            f16* xd = (l & 1) ? xhA : xhB;
            agg_f16<<<NM / 4, 256, 0, stream>>>(xs, offs, ssrc, ab);
            gemm_gru_v10<<<dim3(NM / 64, 8), 256, 0, stream>>>(
                ab, xs, wct + (size_t)l * 768 * 256, whh_h, bih, bhh,
                out, xd, (l == NL - 1) ? 1 : 0, (l < NL - 1) ? 1 : 0);
        }
    } else {
        const float* xs = emb;
        for (int l = 0; l < NL; ++l) {
            agg_f32<<<NM / 4, 256, 0, stream>>>(xs, offs, ssrc, ab);
            gemm_gru_slow<<<dim3(NM / 64, 8), 256, 0, stream>>>(
                ab, wct + (size_t)l * 768 * 256, whh_h, bih, bhh, xs, out);
            xs = out;
        }
    }
}

// Round 16
// 223.769 us; speedup vs baseline: 1.0267x; 1.0146x over previous
//
#include <hip/hip_runtime.h>
#include <hip/hip_bf16.h>

typedef _Float16 f16;
typedef _Float16 f16x4 __attribute__((ext_vector_type(4)));
typedef _Float16 f16x8 __attribute__((ext_vector_type(8)));
typedef float f32x4 __attribute__((ext_vector_type(4)));

#define NB 16
#define NN 1024
#define HH 256
#define NE 16384
#define NL 4
#define NM (NB * NN)   // 16384 rows

// ---------------- small utility kernels ----------------

// fused weight conversion: wih (196608) | whh (196608) | W (262144), all f32->f16,
// 8 elements/thread via float4 pairs. 81920 threads = 320 blocks.
__global__ void cvt_weights(const float* __restrict__ wih, const float* __restrict__ whh,
                            const float* __restrict__ W,
                            f16* __restrict__ wih_h, f16* __restrict__ whh_h,
                            f16* __restrict__ w_h) {
    int i = blockIdx.x * 256 + threadIdx.x;
    const float* s;
    f16* d;
    size_t off;
    if (i < 24576)      { s = wih; d = wih_h; off = (size_t)i * 8; }
    else if (i < 49152) { s = whh; d = whh_h; off = (size_t)(i - 24576) * 8; }
    else                { s = W;   d = w_h;   off = (size_t)(i - 49152) * 8; }
    const float4* p = (const float4*)(s + off);
    float4 a = p[0], b = p[1];
    f16x8 v;
    v[0] = (f16)a.x; v[1] = (f16)a.y; v[2] = (f16)a.z; v[3] = (f16)a.w;
    v[4] = (f16)b.x; v[5] = (f16)b.y; v[6] = (f16)b.z; v[7] = (f16)b.w;
    *(f16x8*)(d + off) = v;
}

__global__ void cvt_f32_f16v(const float* __restrict__ s, f16* __restrict__ d, int n8) {
    int i = blockIdx.x * 256 + threadIdx.x;
    if (i < n8) {
        const float4* p = (const float4*)(s + (size_t)i * 8);
        float4 a = p[0], b = p[1];
        f16x8 v;
        v[0] = (f16)a.x; v[1] = (f16)a.y; v[2] = (f16)a.z; v[3] = (f16)a.w;
        v[4] = (f16)b.x; v[5] = (f16)b.y; v[6] = (f16)b.z; v[7] = (f16)b.w;
        *(f16x8*)(d + (size_t)i * 8) = v;
    }
}

__global__ void zero_i32(int* p, int n) {
    int i = blockIdx.x * 256 + threadIdx.x;
    if (i < n) p[i] = 0;
}

__global__ void hist_kernel(const int* __restrict__ dst, int* cnt) {
    int e = blockIdx.x * 256 + threadIdx.x;
    if (e < NE) atomicAdd(&cnt[dst[e]], 1);
}

__global__ __launch_bounds__(1024) void scan_kernel(const int* __restrict__ cnt,
                                                    int* __restrict__ offs,
                                                    int* __restrict__ cur) {
    __shared__ int s[1024];
    int i = threadIdx.x;
    int c = cnt[i];
    s[i] = c;
    __syncthreads();
    for (int ofs = 1; ofs < 1024; ofs <<= 1) {
        int v = (i >= ofs) ? s[i - ofs] : 0;
        __syncthreads();
        s[i] += v;
        __syncthreads();
    }
    offs[i + 1] = s[i];
    if (i == 0) offs[0] = 0;
    cur[i] = s[i] - c;
}

__global__ void fill_kernel(const int* __restrict__ src, const int* __restrict__ dst,
                            int* cur, int* __restrict__ ssrc) {
    int e = blockIdx.x * 256 + threadIdx.x;
    if (e < NE) {
        int pos = atomicAdd(&cur[dst[e]], 1);
        ssrc[pos] = src[e];
    }
}

// ---------------- Wc = w_ih @ W[l]^T  (per layer), fp16 MFMA ----------------
__global__ __launch_bounds__(256) void wct_gemm(const f16* __restrict__ wih,
                                                const f16* __restrict__ wl,
                                                f16* __restrict__ wct) {
    int wid = threadIdx.x >> 6, lane = threadIdx.x & 63;
    int tile = blockIdx.x * 4 + wid;
    int l = tile / 768, rem = tile % 768;
    int jt = rem / 16, ht = rem % 16;
    const f16* A = wih + (size_t)(jt * 16 + (lane & 15)) * 256 + (lane >> 4) * 8;
    const f16* B = wl + (size_t)l * 65536 + (size_t)(ht * 16 + (lane & 15)) * 256 + (lane >> 4) * 8;
    f32x4 acc;
    for (int r = 0; r < 4; ++r) acc[r] = 0.f;
    for (int k = 0; k < 256; k += 32) {
        f16x8 a = *(const f16x8*)(A + k);
        f16x8 b = *(const f16x8*)(B + k);
        acc = __builtin_amdgcn_mfma_f32_16x16x32_f16(a, b, acc, 0, 0, 0);
    }
    int col = lane & 15, row0 = (lane >> 4) * 4;
    for (int r = 0; r < 4; ++r)
        wct[(size_t)l * 196608 + (size_t)(jt * 16 + row0 + r) * 256 + ht * 16 + col] = (f16)acc[r];
}

// ---------------- aggregation (fast path): XCD-affine per batch ----------------
__global__ __launch_bounds__(256) void agg_f16(const f16* __restrict__ xh,
                                               const int* __restrict__ offs,
                                               const int* __restrict__ ssrc,
                                               f16* __restrict__ ab) {
    int bid = blockIdx.x;
    int b = (bid & 7) + ((bid >> 11) << 3);
    int n = ((bid >> 3) & 255) * 4 + (threadIdx.x >> 6);
    int lane = threadIdx.x & 63;
    const f16* xb = xh + ((size_t)b << 18);
    int e0 = offs[n], e1 = offs[n + 1];
    float s0 = 0.f, s1 = 0.f, s2 = 0.f, s3 = 0.f;
    int p = e0;
    for (; p + 1 < e1; p += 2) {
        int i0 = ssrc[p], i1 = ssrc[p + 1];
        f16x4 v0 = *(const f16x4*)(xb + (((size_t)i0) << 8) + lane * 4);
        f16x4 v1 = *(const f16x4*)(xb + (((size_t)i1) << 8) + lane * 4);
        s0 += (float)v0[0] + (float)v1[0];
        s1 += (float)v0[1] + (float)v1[1];
        s2 += (float)v0[2] + (float)v1[2];
        s3 += (float)v0[3] + (float)v1[3];
    }
    if (p < e1) {
        f16x4 v0 = *(const f16x4*)(xb + (((size_t)ssrc[p]) << 8) + lane * 4);
        s0 += (float)v0[0]; s1 += (float)v0[1]; s2 += (float)v0[2]; s3 += (float)v0[3];
    }
    int row = (b << 10) + n;
    f16x4 o; o[0] = (f16)s0; o[1] = (f16)s1; o[2] = (f16)s2; o[3] = (f16)s3;
    *(f16x4*)(ab + (size_t)row * 256 + lane * 4) = o;
}

// ---------------- aggregation (fallback fp32 path) ----------------
__global__ __launch_bounds__(256) void agg_f32(const float* __restrict__ x,
                                               const int* __restrict__ offs,
                                               const int* __restrict__ ssrc,
                                               f16* __restrict__ ab) {
    int row = blockIdx.x * 4 + (threadIdx.x >> 6);
    int lane = threadIdx.x & 63;
    int b = row >> 10, n = row & 1023;
    int e0 = offs[n], e1 = offs[n + 1];
    float s0 = 0.f, s1 = 0.f, s2 = 0.f, s3 = 0.f;
    const float* xb = x + ((size_t)b << 18);
    for (int p = e0; p < e1; ++p) {
        float4 v = *(const float4*)(xb + (((size_t)ssrc[p]) << 8) + lane * 4);
        s0 += v.x; s1 += v.y; s2 += v.z; s3 += v.w;
    }
    f16x4 o; o[0] = (f16)s0; o[1] = (f16)s1; o[2] = (f16)s2; o[3] = (f16)s3;
    *(f16x4*)(ab + (size_t)row * 512 + lane * 4) = o;
    float4 v = *(const float4*)(x + (size_t)row * 256 + lane * 4);
    f16x4 o2; o2[0] = (f16)v.x; o2[1] = (f16)v.y; o2[2] = (f16)v.z; o2[3] = (f16)v.w;
    *(f16x4*)(ab + (size_t)row * 512 + 256 + lane * 4) = o2;
}

// ---------------- fused GEMM + GRU v10: proven best (R12/R15, ~227 us total) ----------------
// 256 thr / 4 waves arranged wm x wj = 2x2. Tile 64 rows x 32 cols x 6 groups.
// Wave (wm,wj): rows wm*32 + mf*16 (mf=2), cols wj*16. Per wave-step:
// 4 A-reads + 6 B-reads feed 12 MFMAs. Reg-staged LDS (ds_write anchors the
// global loads so the compiler cannot sink them), both-side XOR swizzle
// slot = chunk ^ ((row>>1)&3) (verified 0 bank conflicts), 2 barriers/step,
// t+1 loads issued right after the write-barrier -> full MFMA phase to land.
// 20 KB LDS, grid (256,8) = 2048 blocks = 8 blocks/CU.
__global__ __launch_bounds__(256) void gemm_gru_v10(const f16* __restrict__ ab,
                                                    const f16* __restrict__ xh,
                                                    const f16* __restrict__ wct,
                                                    const f16* __restrict__ whh,
                                                    const float* __restrict__ bih,
                                                    const float* __restrict__ bhh,
                                                    float* __restrict__ out,
                                                    f16* __restrict__ xh_dst,
                                                    int wout, int wxh) {
    __shared__ __align__(16) f16 Ay[64 * 32];    // 4 KB
    __shared__ __align__(16) f16 Ax[64 * 32];    // 4 KB
    __shared__ __align__(16) f16 Bs[192 * 32];   // 12 KB

    const int tid = threadIdx.x;
    const int w = tid >> 6, lane = tid & 63;
    const int wm = w >> 1, wj = w & 1;
    const int fr = lane & 15, sg = lane >> 4;
    const int m0 = blockIdx.x * 64;
    const int j0 = blockIdx.y * 32;

    // ---- staging sources (k-invariant) + swizzled LDS write offsets ----
    const int rA = tid >> 2, cA = tid & 3;
    const f16* gy = ab + (size_t)(m0 + rA) * 256 + cA * 8;
    const f16* gx = xh + (size_t)(m0 + rA) * 256 + cA * 8;
    const int wA = rA * 32 + ((cA ^ ((rA >> 1) & 3)) * 8);
    const f16 *gb0, *gb1, *gb2;
    int wB0, wB1, wB2;
    {
        int u0 = tid, u1 = tid + 256, u2 = tid + 512;
        int rr0 = u0 >> 2, rr1 = u1 >> 2, rr2 = u2 >> 2;
        int g0 = rr0 >> 5, g1 = rr1 >> 5, g2 = rr2 >> 5;
        gb0 = ((g0 < 3) ? (wct + (size_t)(g0 * 256 + j0 + (rr0 & 31)) * 256)
                        : (whh + (size_t)((g0 - 3) * 256 + j0 + (rr0 & 31)) * 256)) + (u0 & 3) * 8;
        gb1 = ((g1 < 3) ? (wct + (size_t)(g1 * 256 + j0 + (rr1 & 31)) * 256)
                        : (whh + (size_t)((g1 - 3) * 256 + j0 + (rr1 & 31)) * 256)) + (u1 & 3) * 8;
        gb2 = ((g2 < 3) ? (wct + (size_t)(g2 * 256 + j0 + (rr2 & 31)) * 256)
                        : (whh + (size_t)((g2 - 3) * 256 + j0 + (rr2 & 31)) * 256)) + (u2 & 3) * 8;
        wB0 = rr0 * 32 + (((u0 & 3) ^ ((rr0 >> 1) & 3)) * 8);
        wB1 = rr1 * 32 + (((u1 & 3) ^ ((rr1 >> 1) & 3)) * 8);
        wB2 = rr2 * 32 + (((u2 & 3) ^ ((rr2 >> 1) & 3)) * 8);
    }

    // ---- swizzled read offsets (f16 units) ----
    int aoff[2];
#pragma unroll
    for (int mf = 0; mf < 2; ++mf) {
        int row = wm * 32 + mf * 16 + fr;
        aoff[mf] = row * 32 + ((sg ^ ((row >> 1) & 3)) * 8);
    }
    int boff[6];
#pragma unroll
    for (int g = 0; g < 6; ++g) {
        int row = g * 32 + wj * 16 + fr;
        boff[g] = row * 32 + ((sg ^ ((row >> 1) & 3)) * 8);
    }

    f32x4 acc[6][2];
#pragma unroll
    for (int g = 0; g < 6; ++g)
#pragma unroll
        for (int mf = 0; mf < 2; ++mf)
#pragma unroll
            for (int r = 0; r < 4; ++r) acc[g][mf][r] = 0.f;

    f16x8 ry, rx, rb0, rb1, rb2;
#define LOADREGS(KK)                          \
    do {                                      \
        ry = *(const f16x8*)(gy + (KK));      \
        rx = *(const f16x8*)(gx + (KK));      \
        rb0 = *(const f16x8*)(gb0 + (KK));    \
        rb1 = *(const f16x8*)(gb1 + (KK));    \
        rb2 = *(const f16x8*)(gb2 + (KK));    \
    } while (0)

    LOADREGS(0);

#pragma unroll
    for (int t = 0; t < 8; ++t) {
        if (t) __syncthreads();            // previous step's readers done
        *(f16x8*)(Ay + wA) = ry;
        *(f16x8*)(Ax + wA) = rx;
        *(f16x8*)(Bs + wB0) = rb0;
        *(f16x8*)(Bs + wB1) = rb1;
        *(f16x8*)(Bs + wB2) = rb2;
        __syncthreads();
        if (t < 7) LOADREGS((t + 1) * 32); // in flight across the MFMA section

        f16x8 aY[2], aX[2];
        aY[0] = *(const f16x8*)(Ay + aoff[0]);
        aY[1] = *(const f16x8*)(Ay + aoff[1]);
        aX[0] = *(const f16x8*)(Ax + aoff[0]);
        aX[1] = *(const f16x8*)(Ax + aoff[1]);
#pragma unroll
        for (int g = 0; g < 6; ++g) {
            f16x8 bF = *(const f16x8*)(Bs + boff[g]);
#pragma unroll
            for (int mf = 0; mf < 2; ++mf) {
                acc[g][mf] = __builtin_amdgcn_mfma_f32_16x16x32_f16(
                    (g < 3) ? aY[mf] : aX[mf], bF, acc[g][mf], 0, 0, 0);
            }
        }
    }
#undef LOADREGS

    // ---- GRU epilogue ----
    const int j = j0 + wj * 16 + fr;
    const float bir = bih[j], biz = bih[j + 256], bin = bih[j + 512];
    const float bhr = bhh[j], bhz = bhh[j + 256], bhn = bhh[j + 512];
#pragma unroll
    for (int mf = 0; mf < 2; ++mf) {
#pragma unroll
        for (int r = 0; r < 4; ++r) {
            int row = m0 + wm * 32 + mf * 16 + sg * 4 + r;
            float gir = acc[0][mf][r] + bir;
            float giz = acc[1][mf][r] + biz;
            float gin = acc[2][mf][r] + bin;
            float ghr = acc[3][mf][r] + bhr;
            float ghz = acc[4][mf][r] + bhz;
            float ghn = acc[5][mf][r] + bhn;
            float rg = 1.f / (1.f + __expf(-(gir + ghr)));
            float zg = 1.f / (1.f + __expf(-(giz + ghz)));
            float ng = tanhf(gin + rg * ghn);
            float h = (float)xh[(size_t)row * 256 + j];
            float res = (1.f - zg) * ng + zg * h;
            if (wout) out[(size_t)row * 256 + j] = res;
            if (wxh) xh_dst[(size_t)row * 256 + j] = (f16)res;
        }
    }
}

// ---------------- old fused GEMM + GRU (fallback fp32 path) ----------------
__global__ __launch_bounds__(256) void gemm_gru_slow(const f16* __restrict__ ab,
                                                     const f16* __restrict__ wct,
                                                     const f16* __restrict__ whh,
                                                     const float* __restrict__ bih,
                                                     const float* __restrict__ bhh,
                                                     const float* __restrict__ x_src,
                                                     float* __restrict__ out) {
    __shared__ __align__(16) f16 As[2][64][40];
    __shared__ __align__(16) f16 Bs[6][32][40];

    int m0 = blockIdx.x * 64;
    int j0 = blockIdx.y * 32;
    int tid = threadIdx.x;
    int wid = tid >> 6, lane = tid & 63;

    f32x4 acc[6][2];
#pragma unroll
    for (int g = 0; g < 6; ++g)
#pragma unroll
        for (int jt = 0; jt < 2; ++jt)
#pragma unroll
            for (int r = 0; r < 4; ++r) acc[g][jt][r] = 0.f;

    int ar = tid >> 2, ac = (tid & 3) * 8;

    for (int kk = 0; kk < 256; kk += 32) {
        f16x8 a0 = *(const f16x8*)(ab + (size_t)(m0 + ar) * 512 + kk + ac);
        f16x8 a1 = *(const f16x8*)(ab + (size_t)(m0 + ar) * 512 + 256 + kk + ac);
        *(f16x8*)(&As[0][ar][ac]) = a0;
        *(f16x8*)(&As[1][ar][ac]) = a1;
#pragma unroll
        for (int i = 0; i < 3; ++i) {
            int idx = tid + i * 256;
            int g = idx >> 7;
            int r = (idx >> 2) & 31;
            int c = (idx & 3) * 8;
            const f16* src = (g < 3)
                ? (wct + (size_t)(j0 + g * 256 + r) * 256 + kk + c)
                : (whh + (size_t)(j0 + (g - 3) * 256 + r) * 256 + kk + c);
            *(f16x8*)(&Bs[g][r][c]) = *(const f16x8*)src;
        }
        __syncthreads();

        int fr = lane & 15, fo = (lane >> 4) * 8;
        f16x8 aF[2];
        aF[0] = *(const f16x8*)(&As[0][wid * 16 + fr][fo]);
        aF[1] = *(const f16x8*)(&As[1][wid * 16 + fr][fo]);
#pragma unroll
        for (int g = 0; g < 6; ++g) {
#pragma unroll
            for (int jt = 0; jt < 2; ++jt) {
                f16x8 bF = *(const f16x8*)(&Bs[g][jt * 16 + fr][fo]);
                acc[g][jt] = __builtin_amdgcn_mfma_f32_16x16x32_f16(
                    (g < 3) ? aF[0] : aF[1], bF, acc[g][jt], 0, 0, 0);
            }
        }
        __syncthreads();
    }

    int fr = lane & 15, frow = (lane >> 4) * 4;
#pragma unroll
    for (int jt = 0; jt < 2; ++jt) {
        int j = j0 + jt * 16 + fr;
        float bir = bih[j], biz = bih[j + 256], bin = bih[j + 512];
        float bhr = bhh[j], bhz = bhh[j + 256], bhn = bhh[j + 512];
#pragma unroll
        for (int r = 0; r < 4; ++r) {
            int row = m0 + wid * 16 + frow + r;
            float gir = acc[0][jt][r] + bir;
            float giz = acc[1][jt][r] + biz;
            float gin = acc[2][jt][r] + bin;
            float ghr = acc[3][jt][r] + bhr;
            float ghz = acc[4][jt][r] + bhz;
            float ghn = acc[5][jt][r] + bhn;
            float rg = 1.f / (1.f + __expf(-(gir + ghr)));
            float zg = 1.f / (1.f + __expf(-(giz + ghz)));
            float ng = tanhf(gin + rg * ghn);
            float h = x_src[(size_t)row * 256 + j];
            out[(size_t)row * 256 + j] = (1.f - zg) * ng + zg * h;
        }
    }
}

// ---------------- launch ----------------

extern "C" void kernel_launch(void* const* d_in, const int* in_sizes, int n_in,
                              void* d_out, int out_size, void* d_ws, size_t ws_size,
                              hipStream_t stream) {
    const float* emb = (const float*)d_in[0];
    const int* eidx = (const int*)d_in[1];
    const float* W = (const float*)d_in[2];
    const float* wih = (const float*)d_in[3];
    const float* whh = (const float*)d_in[4];
    const float* bih = (const float*)d_in[5];
    const float* bhh = (const float*)d_in[6];
    float* out = (float*)d_out;

    const size_t NEL = (size_t)NM * 256;
    f16* ab = (f16*)d_ws;
    f16* xhA = ab + NEL;
    f16* xhB = xhA + NEL;
    f16* wct_f = xhB + NEL;
    const size_t need = ((size_t)3 * NEL + 786432 + 196608 + 196608 + 262144) * 2 + 80000;
    bool fast = ws_size >= need;

    f16 *wct, *whh_h, *wih_h, *w_h;
    if (fast) {
        wct = wct_f;
    } else {
        wct = (f16*)((char*)d_ws + (size_t)16 * 1024 * 1024);
    }
    whh_h = wct + (size_t)4 * 768 * 256;
    wih_h = whh_h + (size_t)768 * 256;
    w_h = wih_h + (size_t)768 * 256;
    int* cnt = (int*)(w_h + (size_t)4 * 256 * 256);
    int* offs = cnt + 1024;
    int* cur = offs + 1056;
    int* ssrc = cur + 1024;

    // fused weight conversion (wih | whh | W), 81920 threads
    cvt_weights<<<320, 256, 0, stream>>>(wih, whh, W, wih_h, whh_h, w_h);

    zero_i32<<<4, 256, 0, stream>>>(cnt, 1024);
    hist_kernel<<<64, 256, 0, stream>>>(eidx + NE, cnt);
    scan_kernel<<<1, 1024, 0, stream>>>(cnt, offs, cur);
    fill_kernel<<<64, 256, 0, stream>>>(eidx, eidx + NE, cur, ssrc);

    wct_gemm<<<768, 256, 0, stream>>>(wih_h, w_h, wct);

    if (fast) {
        cvt_f32_f16v<<<(int)(NEL / 8 + 255) / 256, 256, 0, stream>>>(emb, xhA, (int)(NEL / 8));
        for (int l = 0; l < NL; ++l) {
            f16* xs = (l & 1) ? xhB : xhA;
            f16* xd = (l & 1) ? xhA : xhB;
            agg_f16<<<NM / 4, 256, 0, stream>>>(xs, offs, ssrc, ab);
            gemm_gru_v10<<<dim3(NM / 64, 8), 256, 0, stream>>>(
                ab, xs, wct + (size_t)l * 768 * 256, whh_h, bih, bhh,
                out, xd, (l == NL - 1) ? 1 : 0, (l < NL - 1) ? 1 : 0);
        }
    } else {
        const float* xs = emb;
        for (int l = 0; l < NL; ++l) {
            agg_f32<<<NM / 4, 256, 0, stream>>>(xs, offs, ssrc, ab);
            gemm_gru_slow<<<dim3(NM / 64, 8), 256, 0, stream>>>(
                ab, wct + (size_t)l * 768 * 256, whh_h, bih, bhh, xs, out);
            xs = out;
        }
    }
}